// Round 1
// 135.018 us; speedup vs baseline: 1.0494x; 1.0494x over previous
//
#include <hip/hip_runtime.h>
#include <stdint.h>

// DiffLogic: 3-layer differentiable logic network.
// Round 7: FUSE all three layers. The gate DAG is static and batch-independent:
// each final-layer gate is a fixed depth-3 tree over 8 leaf columns of x.
// A prep kernel flattens the tree (8 leaf indices + 7 coef float4 per gate);
// the fused kernel then evaluates the whole network per gate from the 0.5 MB
// L2-resident xT with f32 intermediates in registers. This deletes h1/h2
// (32.8 MB writes + 65.5 MB cold gathers, twice) entirely at 7/3x recompute,
// which is cheap (VALU was ~3 us/layer).

#define BATCH   256
#define IN_DIM  1024
#define WIDTH   64000
#define NGROUP  10
#define GSIZE   6400      // WIDTH / NGROUP
#define TAU     30.0f
#define NWAVE   16        // waves per block
#define GPW     8         // serial gates per wave
#define GPB     (NWAVE*GPW)   // 128 gates/block; 6400 % 128 == 0
#define NBLK    (WIDTH/GPB)   // 500

typedef unsigned short ushort_t;

static __device__ __forceinline__ float bf2f(ushort_t s) {
    return __uint_as_float((uint32_t)s << 16);
}
static __device__ __forceinline__ ushort_t f2bf(float f) {   // RNE
    uint32_t u = __float_as_uint(f);
    return (ushort_t)((u + 0x7fffu + ((u >> 16) & 1u)) >> 16);
}
static __device__ __forceinline__ float4 up4(ushort4 s) {
    return make_float4(bf2f(s.x), bf2f(s.y), bf2f(s.z), bf2f(s.w));
}
// h = c0 + c1*a + c2*b + c3*(a*b), componentwise over 4 batch elems
static __device__ __forceinline__ float4 gate4(float4 c, float4 a, float4 b) {
    float4 r;
    r.x = fmaf(c.w, a.x * b.x, fmaf(c.z, b.x, fmaf(c.y, a.x, c.x)));
    r.y = fmaf(c.w, a.y * b.y, fmaf(c.z, b.y, fmaf(c.y, a.y, c.x)));
    r.z = fmaf(c.w, a.z * b.z, fmaf(c.z, b.z, fmaf(c.y, a.z, c.x)));
    r.w = fmaf(c.w, a.w * b.w, fmaf(c.z, b.w, fmaf(c.y, a.w, c.x)));
    return r;
}

// ---------------------------------------------------------------- transpose
// x:(256,1024) f32 row-major -> xT:(1024,256) bf16
__global__ __launch_bounds__(256) void transpose_kernel(
    const float* __restrict__ x, ushort_t* __restrict__ xT)
{
    __shared__ float tile[64][65];
    const int c0 = (blockIdx.x & 15) * 64;
    const int b0 = (blockIdx.x >> 4) * 64;
    const int lt = threadIdx.x & 63;
    const int wt = threadIdx.x >> 6;
    for (int r = wt; r < 64; r += 4)
        tile[r][lt] = x[(b0 + r) * IN_DIM + c0 + lt];
    __syncthreads();
    for (int r = wt; r < 64; r += 4)
        xT[(c0 + r) * BATCH + b0 + lt] = f2bf(tile[lt][r]);
}

// ---------------------------------------------------------------- coefficients
__global__ __launch_bounds__(256) void coef_kernel(
    const float* __restrict__ w1, const float* __restrict__ w2,
    const float* __restrict__ w3,
    float4* __restrict__ c1o, float4* __restrict__ c2o, float4* __restrict__ c3o)
{
    const int id = blockIdx.x * 256 + threadIdx.x;
    const int layer = id / WIDTH;
    const int j = id - layer * WIDTH;
    const float* w = (layer == 0) ? w1 : (layer == 1) ? w2 : w3;
    float4* cc     = (layer == 0) ? c1o : (layer == 1) ? c2o : c3o;

    const float4* w4 = (const float4*)(w + (size_t)j * 16);
    float4 q0 = w4[0], q1 = w4[1], q2 = w4[2], q3 = w4[3];
    float p[16] = {q0.x,q0.y,q0.z,q0.w, q1.x,q1.y,q1.z,q1.w,
                   q2.x,q2.y,q2.z,q2.w, q3.x,q3.y,q3.z,q3.w};
    float m = p[0];
    #pragma unroll
    for (int i = 1; i < 16; ++i) m = fmaxf(m, p[i]);
    float s = 0.f;
    #pragma unroll
    for (int i = 0; i < 16; ++i) { p[i] = __expf(p[i] - m); s += p[i]; }
    const float inv = 1.0f / s;

    float c0 = (p[8]+p[9]+p[10]+p[11]+p[12]+p[13]+p[14]+p[15]) * inv;
    float c1 = (p[2]+p[3]+p[6]+p[7] - p[8]-p[9]-p[12]-p[13]) * inv;
    float c2 = (p[4]+p[5]+p[6]+p[7] - p[8]-p[9]-p[10]-p[11]) * inv;
    float c3 = (p[1]-p[2]-p[4]-2.f*p[6]-p[7]+p[8]+2.f*p[9]+p[11]+p[13]-p[14]) * inv;
    cc[j] = make_float4(c0, c1, c2, c3);
}

// ---------------------------------------------------------------- tree prep
// One thread per final-layer gate j: flatten its depth-3 index tree into
// 8 leaf x-indices + 7 coefficient float4s (contiguous per gate).
__global__ __launch_bounds__(256) void prep_kernel(
    const int* __restrict__ ia1, const int* __restrict__ ib1,
    const int* __restrict__ ia2, const int* __restrict__ ib2,
    const int* __restrict__ ia3, const int* __restrict__ ib3,
    const float4* __restrict__ c1, const float4* __restrict__ c2,
    const float4* __restrict__ c3,
    int* __restrict__ leaf,        // [WIDTH][8]
    float4* __restrict__ pc)       // [WIDTH][7]
{
    const int j = blockIdx.x * 256 + threadIdx.x;
    if (j >= WIDTH) return;

    const int pa = ia3[j], pb = ib3[j];
    const int qaa = ia2[pa], qab = ib2[pa];
    const int qba = ia2[pb], qbb = ib2[pb];

    int* L = leaf + (size_t)j * 8;
    L[0] = ia1[qaa]; L[1] = ib1[qaa];
    L[2] = ia1[qab]; L[3] = ib1[qab];
    L[4] = ia1[qba]; L[5] = ib1[qba];
    L[6] = ia1[qbb]; L[7] = ib1[qbb];

    float4* P = pc + (size_t)j * 7;
    P[0] = c1[qaa]; P[1] = c1[qab]; P[2] = c1[qba]; P[3] = c1[qbb];
    P[4] = c2[pa];  P[5] = c2[pb];
    P[6] = c3[j];
}

// ---------------------------------------------------------------- fused net
// Each wave evaluates GPW final gates over the full batch (ushort4/lane).
// All per-gate metadata is wave-uniform -> scalar loads + SGPR column bases.
// Intermediates (h1,h2) live in f32 registers; only leaves are bf16.
__global__ __launch_bounds__(1024) void fused_kernel(
    const ushort_t* __restrict__ xT,
    const int*      __restrict__ leaf,
    const float4*   __restrict__ pc,
    float*          __restrict__ red_out)
{
    const int lane = threadIdx.x & 63;
    const int wave = __builtin_amdgcn_readfirstlane(threadIdx.x >> 6);
    const int jw = blockIdx.x * GPB + wave * GPW;

    float4 acc = make_float4(0.f, 0.f, 0.f, 0.f);

    #pragma unroll 2
    for (int u = 0; u < GPW; ++u) {
        const int j = jw + u;
        const int* Lp = leaf + (size_t)j * 8;
        // wave-uniform leaf indices -> force SGPR so gathers use saddr form
        const int l0 = __builtin_amdgcn_readfirstlane(Lp[0]);
        const int l1 = __builtin_amdgcn_readfirstlane(Lp[1]);
        const int l2 = __builtin_amdgcn_readfirstlane(Lp[2]);
        const int l3 = __builtin_amdgcn_readfirstlane(Lp[3]);
        const int l4 = __builtin_amdgcn_readfirstlane(Lp[4]);
        const int l5 = __builtin_amdgcn_readfirstlane(Lp[5]);
        const int l6 = __builtin_amdgcn_readfirstlane(Lp[6]);
        const int l7 = __builtin_amdgcn_readfirstlane(Lp[7]);

        // 8 leaf column gathers: 512B contiguous per wave, L2-resident xT
        const ushort4 v0 = ((const ushort4*)(xT + (size_t)l0 * BATCH))[lane];
        const ushort4 v1 = ((const ushort4*)(xT + (size_t)l1 * BATCH))[lane];
        const ushort4 v2 = ((const ushort4*)(xT + (size_t)l2 * BATCH))[lane];
        const ushort4 v3 = ((const ushort4*)(xT + (size_t)l3 * BATCH))[lane];
        const ushort4 v4 = ((const ushort4*)(xT + (size_t)l4 * BATCH))[lane];
        const ushort4 v5 = ((const ushort4*)(xT + (size_t)l5 * BATCH))[lane];
        const ushort4 v6 = ((const ushort4*)(xT + (size_t)l6 * BATCH))[lane];
        const ushort4 v7 = ((const ushort4*)(xT + (size_t)l7 * BATCH))[lane];

        const float4* Pp = pc + (size_t)j * 7;     // uniform -> s_load
        const float4 C1aa = Pp[0], C1ab = Pp[1], C1ba = Pp[2], C1bb = Pp[3];
        const float4 C2a  = Pp[4], C2b  = Pp[5], C3c = Pp[6];

        const float4 haa = gate4(C1aa, up4(v0), up4(v1));
        const float4 hab = gate4(C1ab, up4(v2), up4(v3));
        const float4 hba = gate4(C1ba, up4(v4), up4(v5));
        const float4 hbb = gate4(C1bb, up4(v6), up4(v7));
        const float4 h2a = gate4(C2a, haa, hab);
        const float4 h2b = gate4(C2b, hba, hbb);
        const float4 h3  = gate4(C3c, h2a, h2b);
        acc.x += h3.x; acc.y += h3.y; acc.z += h3.z; acc.w += h3.w;
    }

    __shared__ float4 s[NWAVE][64];     // 16 KB
    s[wave][lane] = acc;
    __syncthreads();
    if (wave == 0) {
        float4 t = s[0][lane];
        #pragma unroll
        for (int w = 1; w < NWAVE; ++w) {
            float4 q = s[w][lane];
            t.x += q.x; t.y += q.y; t.z += q.z; t.w += q.w;
        }
        const float sc = 1.0f / TAU;
        const int grp = (blockIdx.x * GPB) / GSIZE;   // block within one group
        const int b0 = lane * 4;
        atomicAdd(&red_out[(b0 + 0) * NGROUP + grp], t.x * sc);
        atomicAdd(&red_out[(b0 + 1) * NGROUP + grp], t.y * sc);
        atomicAdd(&red_out[(b0 + 2) * NGROUP + grp], t.z * sc);
        atomicAdd(&red_out[(b0 + 3) * NGROUP + grp], t.w * sc);
    }
}

// ---------------------------------------------------------------- launch
extern "C" void kernel_launch(void* const* d_in, const int* in_sizes, int n_in,
                              void* d_out, int out_size, void* d_ws, size_t ws_size,
                              hipStream_t stream)
{
    const float* x   = (const float*)d_in[0];
    const float* w1  = (const float*)d_in[1];
    const float* w2  = (const float*)d_in[2];
    const float* w3  = (const float*)d_in[3];
    const int*   ia1 = (const int*)d_in[4];
    const int*   ib1 = (const int*)d_in[5];
    const int*   ia2 = (const int*)d_in[6];
    const int*   ib2 = (const int*)d_in[7];
    const int*   ia3 = (const int*)d_in[8];
    const int*   ib3 = (const int*)d_in[9];
    float* out = (float*)d_out;

    // workspace (byte offsets, 16B-aligned):
    // xT (0.5MB) | c1|c2|c3 (3MB) | leaf (2MB) | pc (7MB)  ~= 12.5 MB
    char* ws = (char*)d_ws;
    ushort_t* xT = (ushort_t*)ws;
    float*    c1 = (float*)(ws + (size_t)IN_DIM * BATCH * 2);
    float*    c2 = c1 + (size_t)WIDTH * 4;
    float*    c3 = c2 + (size_t)WIDTH * 4;
    int*    leaf = (int*)(c3 + (size_t)WIDTH * 4);
    float4*   pc = (float4*)(leaf + (size_t)WIDTH * 8);

    hipMemsetAsync(d_out, 0, (size_t)out_size * sizeof(float), stream);

    transpose_kernel<<<64, 256, 0, stream>>>(x, xT);
    coef_kernel<<<(3 * WIDTH) / 256, 256, 0, stream>>>(w1, w2, w3,
                                                       (float4*)c1, (float4*)c2, (float4*)c3);
    prep_kernel<<<WIDTH / 256, 256, 0, stream>>>(ia1, ib1, ia2, ib2, ia3, ib3,
                                                 (const float4*)c1, (const float4*)c2,
                                                 (const float4*)c3, leaf, pc);
    fused_kernel<<<NBLK, 1024, 0, stream>>>(xT, leaf, pc, out);
}